// Round 11
// baseline (675.480 us; speedup 1.0000x reference)
//
#include <hip/hip_runtime.h>
#include <math.h>

#define D_MODEL 1024
#define SEQ     2048
#define NB      2
#define NH      16
#define HD      64
#define BH      (NB*NH)      // 32
#define M_TOK   (NB*SEQ)     // 4096
#define KSEL    204          // int(2048 * 0.1)
#define TQ      16           // query rows per attention block
#define LCAP    256          // kept-list cap (204 + bin tail headroom)
#define CCAP    96           // candidate-pool cap per row
#define KPW     256          // keys per wave

typedef __attribute__((ext_vector_type(8))) short bf16x8;   // 8 bf16 (4 VGPRs)
typedef __attribute__((ext_vector_type(4))) float f32x4;    // 4 fp32 acc
typedef __attribute__((ext_vector_type(4))) unsigned short us4;
typedef __attribute__((ext_vector_type(8))) unsigned short us8;

__device__ __forceinline__ unsigned short f2bf(float x) {   // RNE fp32->bf16
    unsigned u = __float_as_uint(x);
    return (unsigned short)((u + 0x7FFFu + ((u >> 16) & 1u)) >> 16);
}
__device__ __forceinline__ float bf2f(unsigned short h) {
    return __uint_as_float(((unsigned)h) << 16);
}

// Integer bin map on the 24-bit fixed-point score e (= rint(d * 2^18)):
// bin = clamp((e + 2^22) >> 15, 0, 255). Pure int ALU, identical in passes
// A and B -> bitwise self-consistent selection.
__device__ __forceinline__ int binOfE(int e) {
    int b = (e + 4194304) >> 15;
    return b < 0 ? 0 : (b > 255 ? 255 : b);
}

// 16B async global->LDS copy. LDS dest is wave-uniform base + lane*16.
__device__ __forceinline__ void gload_lds16(const unsigned short* g,
                                            unsigned short* l) {
    __builtin_amdgcn_global_load_lds(
        (const __attribute__((address_space(1))) unsigned int*)g,
        (__attribute__((address_space(3))) unsigned int*)l, 16, 0, 0);
}

// ---------------------------------------------------------------------------
// Preconvert: fp32 -> (hi, lo) bf16 planes.
// ---------------------------------------------------------------------------
__global__ __launch_bounds__(256) void preconv3_kernel(
    const float* __restrict__ s0, const float* __restrict__ s1,
    const float* __restrict__ s2,
    unsigned short* __restrict__ h0, unsigned short* __restrict__ l0,
    unsigned short* __restrict__ h1, unsigned short* __restrict__ l1,
    unsigned short* __restrict__ h2, unsigned short* __restrict__ l2)
{
    const float* src; unsigned short* hi; unsigned short* lo;
    if (blockIdx.y == 0)      { src = s0; hi = h0; lo = l0; }
    else if (blockIdx.y == 1) { src = s1; hi = h1; lo = l1; }
    else                      { src = s2; hi = h2; lo = l2; }
    int i = (blockIdx.x * 256 + threadIdx.x) * 4;
    float4 v = *(const float4*)(src + i);
    float e[4] = {v.x, v.y, v.z, v.w};
    us4 h, l;
#pragma unroll
    for (int k = 0; k < 4; ++k) {
        unsigned short hh = f2bf(e[k]);
        h[k] = hh; l[k] = f2bf(e[k] - bf2f(hh));
    }
    *(us4*)(hi + i) = h;
    *(us4*)(lo + i) = l;
}

__global__ __launch_bounds__(256) void preconv1_kernel(
    const float* __restrict__ src,
    unsigned short* __restrict__ hi, unsigned short* __restrict__ lo)
{
    int i = (blockIdx.x * 256 + threadIdx.x) * 4;
    float4 v = *(const float4*)(src + i);
    float e[4] = {v.x, v.y, v.z, v.w};
    us4 h, l;
#pragma unroll
    for (int k = 0; k < 4; ++k) {
        unsigned short hh = f2bf(e[k]);
        h[k] = hh; l[k] = f2bf(e[k] - bf2f(hh));
    }
    *(us4*)(hi + i) = h;
    *(us4*)(lo + i) = l;
}

// ---------------------------------------------------------------------------
// Split-bf16 MFMA NT-GEMM, double-buffered LDS 2-phase pipeline (R9 form).
// R11: q/k projections drop the lo x lo term (TERMS 4 -> 3): it contributes
// ~2^-16 relative to q/k (score shift ~1.3e-5, 40x below the quantization
// window that failed in R2) -> absmax shift ~5e-5 against 1.57e-3 margin.
// ---------------------------------------------------------------------------
template<int MODE, int TERMS, int AF32>
__device__ __forceinline__ void mfma_gemm_body(
    const float* __restrict__ Xf,
    const unsigned short* __restrict__ XH, const unsigned short* __restrict__ XL,
    const unsigned short* __restrict__ WH, const unsigned short* __restrict__ WL,
    const float* __restrict__ bias,
    float* __restrict__ Cf, unsigned short* __restrict__ Chi,
    unsigned short* __restrict__ Clo, unsigned short* lds)
{
    const int tid  = threadIdx.x;
    const int lane = tid & 63;
    const int w    = tid >> 6;
    const int mq   = w & 1;
    const int nq   = w >> 1;
    const int m0   = blockIdx.y * 128;
    const int n0   = blockIdx.x * 128;

    auto stageB = [&](int buf, int k0) {
#pragma unroll
        for (int r2 = 0; r2 < 2; ++r2) {
            int m = tid + 256 * r2;
            int fi = (m & 0x1C0) | ((m & 15) << 2) | ((m >> 4) & 3);
            int row = fi >> 2, k8 = fi & 3;
            size_t g = (size_t)(n0 + row) * D_MODEL + k0 + k8 * 8;
            int ldsb = (r2 * 256 + (tid & ~63)) * 8;   // wave-uniform (shorts)
            gload_lds16(WH + g, lds + buf * 16384 + 8192 + ldsb);
            gload_lds16(WL + g, lds + buf * 16384 + 12288 + ldsb);
        }
    };
    auto stageAcopy = [&](int buf, int k0) {
#pragma unroll
        for (int r2 = 0; r2 < 2; ++r2) {
            int m = tid + 256 * r2;
            int fi = (m & 0x1C0) | ((m & 15) << 2) | ((m >> 4) & 3);
            int row = fi >> 2, k8 = fi & 3;
            size_t g = (size_t)(m0 + row) * D_MODEL + k0 + k8 * 8;
            int ldsb = (r2 * 256 + (tid & ~63)) * 8;
            gload_lds16(XH + g, lds + buf * 16384 + ldsb);
            gload_lds16(XL + g, lds + buf * 16384 + 4096 + ldsb);
        }
    };
    auto loadA = [&](int k0, float4* xa) {
#pragma unroll
        for (int r = 0; r < 4; ++r) {
            int f = tid + 256 * r;
            int row = f >> 3, q4 = f & 7;
            xa[r] = *(const float4*)(Xf + (size_t)(m0 + row) * D_MODEL + k0 + q4 * 4);
        }
    };
    auto writeA = [&](int buf, const float4* xa) {
        unsigned short* Ah = lds + buf * 16384;
        unsigned short* Al = Ah + 4096;
#pragma unroll
        for (int r = 0; r < 4; ++r) {
            int f = tid + 256 * r;
            int row = f >> 3, q4 = f & 7;
            int off = (row >> 4) * 512 + ((row & 15) + (q4 >> 1) * 16) * 8 + (q4 & 1) * 4;
            float ax[4] = {xa[r].x, xa[r].y, xa[r].z, xa[r].w};
            us4 ahv, alv;
#pragma unroll
            for (int e = 0; e < 4; ++e) {
                unsigned short h1 = f2bf(ax[e]);
                ahv[e] = h1; alv[e] = f2bf(ax[e] - bf2f(h1));
            }
            *(us4*)(Ah + off) = ahv;  *(us4*)(Al + off) = alv;
        }
    };

    f32x4 acc[4][4];
#pragma unroll
    for (int i = 0; i < 4; ++i)
#pragma unroll
        for (int j = 0; j < 4; ++j) acc[i][j] = (f32x4){0.f, 0.f, 0.f, 0.f};

    // prologue: stage k0=0 into buffer 0
    float4 xa[4];
    if (AF32) loadA(0, xa);
    stageB(0, 0);
    if (!AF32) stageAcopy(0, 0);
    if (AF32) writeA(0, xa);
    __syncthreads();                          // drains vmcnt + lgkm

    int cur = 0;
    for (int k0 = 0; k0 < D_MODEL; k0 += 32) {
        const bool hasNext = (k0 + 32) < D_MODEL;
        if (hasNext) {
            if (AF32) loadA(k0 + 32, xa);     // issue early (reg-private)
            stageB(cur ^ 1, k0 + 32);         // async into other buffer
            if (!AF32) stageAcopy(cur ^ 1, k0 + 32);
        }

        unsigned short* Ah = lds + cur * 16384;
        unsigned short* Al = Ah + 4096;
        unsigned short* Bh = Ah + 8192;
        unsigned short* Bl = Ah + 12288;
        bf16x8 fah[4], fal[4], fbh[4], fbl[4];
#pragma unroll
        for (int i = 0; i < 4; ++i) {
            fah[i] = *(const bf16x8*)(Ah + (mq * 4 + i) * 512 + lane * 8);
            fal[i] = *(const bf16x8*)(Al + (mq * 4 + i) * 512 + lane * 8);
            fbh[i] = *(const bf16x8*)(Bh + (nq * 4 + i) * 512 + lane * 8);
            fbl[i] = *(const bf16x8*)(Bl + (nq * 4 + i) * 512 + lane * 8);
        }
#pragma unroll
        for (int i = 0; i < 4; ++i)
#pragma unroll
            for (int j = 0; j < 4; ++j) {
                acc[i][j] = __builtin_amdgcn_mfma_f32_16x16x32_bf16(fah[i], fbh[j], acc[i][j], 0, 0, 0);
                acc[i][j] = __builtin_amdgcn_mfma_f32_16x16x32_bf16(fah[i], fbl[j], acc[i][j], 0, 0, 0);
                acc[i][j] = __builtin_amdgcn_mfma_f32_16x16x32_bf16(fal[i], fbh[j], acc[i][j], 0, 0, 0);
                if (TERMS == 4)
                    acc[i][j] = __builtin_amdgcn_mfma_f32_16x16x32_bf16(fal[i], fbl[j], acc[i][j], 0, 0, 0);
            }

        if (hasNext && AF32) writeA(cur ^ 1, xa);   // loads have landed
        __syncthreads();                      // next buffer ready; cur free
        cur ^= 1;
    }

    const int quad = lane >> 4;
    const int rl   = lane & 15;
#pragma unroll
    for (int jt = 0; jt < 4; ++jt) {
        int n = n0 + nq * 64 + jt * 16 + rl;
        float bn = bias[n];
        int h = n >> 6, dd = n & 63;
#pragma unroll
        for (int it = 0; it < 4; ++it) {
#pragma unroll
            for (int r = 0; r < 4; ++r) {
                int m = m0 + mq * 64 + it * 16 + quad * 4 + r;
                float v = acc[it][jt][r] + bn;
                if (MODE == 0) {
                    Cf[(size_t)m * D_MODEL + n] = v;
                } else {
                    int b = m >> 11, s = m & 2047;
                    size_t o = (size_t)(((b << 4) + h) * SEQ + s) * HD + dd;
                    if (MODE == 1) {
                        Cf[o] = v;
                    } else {
                        unsigned short hi = f2bf(v);
                        Chi[o] = hi;
                        Clo[o] = f2bf(v - bf2f(hi));
                    }
                }
            }
        }
    }
}

__global__ __launch_bounds__(256) void proj_qkv_kernel(
    const float* __restrict__ qin, const float* __restrict__ kin, const float* __restrict__ vin,
    const unsigned short* __restrict__ wqh, const unsigned short* __restrict__ wql,
    const unsigned short* __restrict__ wkh, const unsigned short* __restrict__ wkl,
    const unsigned short* __restrict__ wvh, const unsigned short* __restrict__ wvl,
    const float* __restrict__ bq, const float* __restrict__ bk, const float* __restrict__ bv,
    unsigned short* qhi, unsigned short* qlo,
    unsigned short* khi, unsigned short* klo,
    float* vws)
{
    __shared__ unsigned short lds[32768];     // 2 x 32 KB buffers
    if (blockIdx.z == 0)
        mfma_gemm_body<2, 3, 1>(qin, nullptr, nullptr, wqh, wql, bq,
                                nullptr, qhi, qlo, lds);
    else if (blockIdx.z == 1)
        mfma_gemm_body<2, 3, 1>(kin, nullptr, nullptr, wkh, wkl, bk,
                                nullptr, khi, klo, lds);
    else
        mfma_gemm_body<1, 3, 1>(vin, nullptr, nullptr, wvh, wvl, bv,
                                vws, nullptr, nullptr, lds);
}

__global__ __launch_bounds__(256) void oproj_kernel(
    const unsigned short* __restrict__ AH, const unsigned short* __restrict__ AL,
    const unsigned short* __restrict__ woh, const unsigned short* __restrict__ wol,
    const float* __restrict__ bo, float* __restrict__ out)
{
    __shared__ unsigned short lds[32768];
    mfma_gemm_body<0, 3, 0>(nullptr, AH, AL, woh, wol, bo,
                            out, nullptr, nullptr, lds);
}

// ---------------------------------------------------------------------------
// Attention (round 22): R10 structure kept (register thresholds, PV 16-wide,
// 437 us). One change: the Pass-A histogram is split into two banks by wave
// group (waves 0-3 -> hist[0], 4-7 -> hist[1]); the scan sums both. Counts
// are identical -> selection bitwise unchanged. Halves the same-address/
// same-bank atomic collision arity on the DS pipe (32 -> 16 lanes per row
// histogram), attacking the serialized LDS-atomic cost of the 32768
// histogram increments per block. LDS: 2*16*260*4 = 33280 B, still under
// the 38912 B union partner.
// ---------------------------------------------------------------------------
__global__ __launch_bounds__(512, 4) void attn_kernel(
    const unsigned short* __restrict__ qhi, const unsigned short* __restrict__ qlo,
    const unsigned short* __restrict__ khi, const unsigned short* __restrict__ klo,
    const float* __restrict__ vws,
    unsigned short* __restrict__ awsHi, unsigned short* __restrict__ awsLo)
{
    __shared__ union __align__(16) UU {
        int hist[2][TQ][260];                       // 33280 B (pass A + scan)
        struct {
            int2  L[TQ][LCAP];                      // 32768 B {key, d_bits}
            float cand[TQ][CCAP];                   // 6144 B
        } p;                                        // 38912 B
    } u;
    __shared__ int   kneedS[TQ];
    __shared__ int   sbinS[TQ];
    __shared__ int   candCnt[TQ];
    __shared__ int   cnt[TQ];

    const int tid  = threadIdx.x;
    const int lane = tid & 63;
    const int w    = tid >> 6;                      // wave 0..7
    const int quad = lane >> 4;                     // 0..3
    const int rl   = lane & 15;                     // this lane's q row
    const int flat = blockIdx.x;
    const int bh   = (flat & 7) * 4 + ((flat >> 3) & 3);   // XCD swizzle
    const int q0   = (flat >> 5) * TQ;
    const size_t hb = (size_t)bh * SEQ * HD;

    {   // clear both histogram banks + per-row state
        int* hp = &u.hist[0][0][0];
        for (int i = tid; i < 2 * TQ * 260; i += 512) hp[i] = 0;
        if (tid < TQ) { candCnt[tid] = 0; cnt[tid] = 0; }
    }

    // q fragments (B operand; col = q row = rl)
    const size_t qoff = hb + (size_t)(q0 + rl) * HD + quad * 8;
    bf16x8 bqh0 = *(const bf16x8*)(qhi + qoff);
    bf16x8 bql0 = *(const bf16x8*)(qlo + qoff);
    bf16x8 bqh1 = *(const bf16x8*)(qhi + qoff + 32);
    bf16x8 bql1 = *(const bf16x8*)(qlo + qoff + 32);

    const int kbase = w * KPW;
    const int hbk   = w >> 2;                       // histogram bank 0/1
    __syncthreads();                                // clear visible

    // ---- Pass A: unscaled scores -> 24-bit register cache + histogram ----
    unsigned scp[48];
#pragma unroll
    for (int t = 0; t < 16; ++t) {
        const size_t koff = hb + (size_t)(kbase + t * 16 + rl) * HD + quad * 8;
        bf16x8 ah0 = *(const bf16x8*)(khi + koff);
        bf16x8 al0 = *(const bf16x8*)(klo + koff);
        bf16x8 ah1 = *(const bf16x8*)(khi + koff + 32);
        bf16x8 al1 = *(const bf16x8*)(klo + koff + 32);
        f32x4 d0 = {0.f, 0.f, 0.f, 0.f};
        f32x4 d1 = {0.f, 0.f, 0.f, 0.f};
        d0 = __builtin_amdgcn_mfma_f32_16x16x32_bf16(ah0, bqh0, d0, 0, 0, 0);
        d1 = __builtin_amdgcn_mfma_f32_16x16x32_bf16(ah1, bqh1, d1, 0, 0, 0);
        d0 = __builtin_amdgcn_mfma_f32_16x16x32_bf16(ah0, bql0, d0, 0, 0, 0);
        d1 = __builtin_amdgcn_mfma_f32_16x16x32_bf16(ah1, bql1, d1, 0, 0, 0);
        d0 = __builtin_amdgcn_mfma_f32_16x16x32_bf16(al0, bqh0, d0, 0, 0, 0);
        d1 = __builtin_amdgcn_mfma_f32_16x16x32_bf16(al1, bqh1, d1, 0, 0, 0);
        f32x4 d = d0 + d1;
        int e[4];
#pragma unroll
        for (int r = 0; r < 4; ++r) {
            e[r] = (int)__builtin_rintf(d[r] * 262144.f);   // 2^18 encode, RNE
            atomicAdd(&u.hist[hbk][rl][binOfE(e[r])], 1);
        }
        // pack 4 x 24-bit -> 3 dwords (little-endian byte stream)
        scp[3*t+0] = ((unsigned)e[0] & 0xFFFFFFu) | ((unsigned)e[1] << 24);
        scp[3*t+1] = (((unsigned)e[1] >> 8) & 0xFFFFu) | ((unsigned)e[2] << 16);
        scp[3*t+2] = (((unsigned)e[2] >> 16) & 0xFFu) | ((unsigned)e[3] << 8);
    }
    __syncthreads();

    // ---- Scan: wave w handles rows w, w+8; suffix-sum over 256 bins ----
#pragma unroll
    for (int half = 0; half < 2; ++half) {
        int r = w + half * 8;
        int4 ha = *(const int4*)&u.hist[0][r][4 * lane];
        int4 hbv = *(const int4*)&u.hist[1][r][4 * lane];
        int h0 = ha.x + hbv.x, h1 = ha.y + hbv.y;
        int h2 = ha.z + hbv.z, h3 = ha.w + hbv.w;
        int s3 = h3, s2 = h2 + s3, s1 = h1 + s2, s0 = h0 + s1;
        int acc = s0;
#pragma unroll
        for (int off = 1; off < 64; off <<= 1) {
            int v = __shfl_down(acc, off);
            acc += (lane + off < 64) ? v : 0;
        }
        int ehi = acc - s0;
        int suf0 = ehi + s0, suf1 = ehi + s1, suf2 = ehi + s2, suf3 = ehi + s3;
        int selbin = -1, newkn = 0;
        if      (suf3 >= KSEL) { selbin = 4*lane + 3; newkn = KSEL - (suf3 - h3); }
        else if (suf2 >= KSEL) { selbin = 4*lane + 2; newkn = KSEL - (suf2 - h2); }
        else if (suf1 >= KSEL) { selbin = 4*lane + 1; newkn = KSEL - (suf1 - h1); }
        else if (suf0 >= KSEL) { selbin = 4*lane + 0; newkn = KSEL - (suf0 - h0); }
        int pack = ((selbin + 1) << 16) | (newkn & 0xFFFF);
#pragma unroll
        for (int off = 32; off; off >>= 1) {
            int o = __shfl_xor(pack, off);
            pack = pack > o ? pack : o;
        }
        if (lane == 0) {
            sbinS[r]  = (pack >> 16) - 1;
            kneedS[r] = pack & 0xFFFF;
        }
    }
    __syncthreads();                                // hist reads done

    // ---- Pass B (register replay): push {key, d} where bin >= sbin ----
    {
        const int sb = sbinS[rl];
#pragma unroll
        for (int t = 0; t < 16; ++t) {
            unsigned p0 = scp[3*t+0], p1 = scp[3*t+1], p2 = scp[3*t+2];
            int e[4];
            e[0] = ((int)(p0 << 8)) >> 8;
            e[1] = ((int)(((p1 << 8) | (p0 >> 24)) << 8)) >> 8;
            e[2] = ((int)(((p2 << 16) | (p1 >> 16)) << 8)) >> 8;
            e[3] = ((int)p2) >> 8;
#pragma unroll
            for (int r = 0; r < 4; ++r) {
                int b = binOfE(e[r]);
                if (b >= sb) {
                    float dv = (float)e[r] * (1.f / 262144.f);
                    int key = kbase + t * 16 + quad * 4 + r;
                    int pos = atomicAdd(&cnt[rl], 1);
                    if (pos < LCAP)
                        u.p.L[rl][pos] = make_int2(key, __float_as_int(dv));
                    if (b == sb) {
                        int cp = atomicAdd(&candCnt[rl], 1);
                        if (cp < CCAP) u.p.cand[rl][cp] = dv;
                    }
                }
            }
        }
    }
    __syncthreads();

    // ---- Exact k-th largest among candidates: rows w, w+8 (in-register) ----
    float bestA = -1e30f, bestB = -1e30f;
#pragma unroll
    for (int half = 0; half < 2; ++half) {
        int r = w + half * 8;
        int n = candCnt[r]; if (n > CCAP) n = CCAP;
        int kn = kneedS[r];
        bool  a0 = lane < n, a1 = lane + 64 < n;
        float x0 = a0 ? u.p.cand[r][lane]      : 0.f;
        float x1 = a1 ? u.p.cand[r][lane + 64] : 0.f;
        int g0 = 0, e0 = 0, g1 = 0, e1 = 0;
        for (int j = 0; j < n; ++j) {
            float c = u.p.cand[r][j];
            g0 += (c > x0);  e0 += (c == x0);
            g1 += (c > x1);  e1 += (c == x1);
        }
        float best = -1e30f;
        if (a0 && g0 < kn && g0 + e0 >= kn) best = x0;
        if (a1 && g1 < kn && g1 + e1 >= kn) best = best > x1 ? best : x1;
#pragma unroll
        for (int off = 32; off; off >>= 1) {
            float o = __shfl_xor(best, off);
            best = best > o ? best : o;
        }
        if (half == 0) bestA = best; else bestB = best;
    }
    // No barrier: PV reads only this wave's registers + L (stable since the
    // post-Pass-B barrier); PV writes no LDS.

    // ---- Phase 4: PV gather, 16 keys/iter, 8 independent V-load chains ----
    {
        const int b = bh >> 4, h = bh & 15;
        const int slot = lane >> 4;                 // 0..3: key sub-slot
        const int d16  = lane & 15;                 // dim quarter (float4)
        const float* Vp = vws + hb + d16 * 4;

        const int r0 = w, r1 = w + 8;
        int n0 = cnt[r0]; if (n0 > LCAP) n0 = LCAP;
        int n1 = cnt[r1]; if (n1 > LCAP) n1 = LCAP;
        const float t0 = bestA, t1 = bestB;
        const int nmax = n0 > n1 ? n0 : n1;
        f32x4 a0 = {0.f,0.f,0.f,0.f}, a1 = {0.f,0.f,0.f,0.f};
        float z0 = 0.f, z1 = 0.f;

        for (int j = 0; j < nmax; j += 16) {
            int ia = j + slot, ib = j + 4 + slot;
            int ic = j + 8 + slot, id = j + 12 + slot;
            int2 p0a = u.p.L[r0][ia < n0 ? ia : 0];
            int2 p0b = u.p.L[r0][ib < n0 ? ib : 0];
            int2 p0c = u.p.L[r0][ic < n0 ? ic : 0];
            int2 p0d = u.p.L[r0][id < n0 ? id : 0];
            int2 p1a = u.p.L[r1][ia < n1 ? ia : 0];
            int2 p1b = u.p.L[r1][ib < n1 ? ib : 0];
            int2 p1c = u.p.L[r1][ic < n1 ? ic : 0];
            int2 p1d = u.p.L[r1][id < n1 ? id : 0];
            float s0a = __int_as_float(p0a.y), s0b = __int_as_float(p0b.y);
            float s0c = __int_as_float(p0c.y), s0d = __int_as_float(p0d.y);
            float s1a = __int_as_float(p1a.y), s1b = __int_as_float(p1b.y);
            float s1c = __int_as_float(p1c.y), s1d = __int_as_float(p1d.y);
            float w0a = ((ia < n0) && (s0a >= t0))
                        ? __builtin_amdgcn_exp2f((s0a - t0) * 0.1803368801f) : 0.f;
            float w0b = ((ib < n0) && (s0b >= t0))
                        ? __builtin_amdgcn_exp2f((s0b - t0) * 0.1803368801f) : 0.f;
            float w0c = ((ic < n0) && (s0c >= t0))
                        ? __builtin_amdgcn_exp2f((s0c - t0) * 0.1803368801f) : 0.f;
            float w0d = ((id < n0) && (s0d >= t0))
                        ? __builtin_amdgcn_exp2f((s0d - t0) * 0.1803368801f) : 0.f;
            float w1a = ((ia < n1) && (s1a >= t1))
                        ? __builtin_amdgcn_exp2f((s1a - t1) * 0.1803368801f) : 0.f;
            float w1b = ((ib < n1) && (s1b >= t1))
                        ? __builtin_amdgcn_exp2f((s1b - t1) * 0.1803368801f) : 0.f;
            float w1c = ((ic < n1) && (s1c >= t1))
                        ? __builtin_amdgcn_exp2f((s1c - t1) * 0.1803368801f) : 0.f;
            float w1d = ((id < n1) && (s1d >= t1))
                        ? __builtin_amdgcn_exp2f((s1d - t1) * 0.1803368801f) : 0.f;
            float4 v0a = *(const float4*)(Vp + (size_t)p0a.x * HD);
            float4 v0b = *(const float4*)(Vp + (size_t)p0b.x * HD);
            float4 v0c = *(const float4*)(Vp + (size_t)p0c.x * HD);
            float4 v0d = *(const float4*)(Vp + (size_t)p0d.x * HD);
            float4 v1a = *(const float4*)(Vp + (size_t)p1a.x * HD);
            float4 v1b = *(const float4*)(Vp + (size_t)p1b.x * HD);
            float4 v1c = *(const float4*)(Vp + (size_t)p1c.x * HD);
            float4 v1d = *(const float4*)(Vp + (size_t)p1d.x * HD);
            a0[0] += (w0a * v0a.x + w0b * v0b.x) + (w0c * v0c.x + w0d * v0d.x);
            a0[1] += (w0a * v0a.y + w0b * v0b.y) + (w0c * v0c.y + w0d * v0d.y);
            a0[2] += (w0a * v0a.z + w0b * v0b.z) + (w0c * v0c.z + w0d * v0d.z);
            a0[3] += (w0a * v0a.w + w0b * v0b.w) + (w0c * v0c.w + w0d * v0d.w);
            a1[0] += (w1a * v1a.x + w1b * v1b.x) + (w1c * v1c.x + w1d * v1d.x);
            a1[1] += (w1a * v1a.y + w1b * v1b.y) + (w1c * v1c.y + w1d * v1d.y);
            a1[2] += (w1a * v1a.z + w1b * v1b.z) + (w1c * v1c.z + w1d * v1d.z);
            a1[3] += (w1a * v1a.w + w1b * v1b.w) + (w1c * v1c.w + w1d * v1d.w);
            z0 += (w0a + w0b) + (w0c + w0d);
            z1 += (w1a + w1b) + (w1c + w1d);
        }
#pragma unroll
        for (int off = 16; off < 64; off <<= 1) {
            a0[0] += __shfl_xor(a0[0], off); a0[1] += __shfl_xor(a0[1], off);
            a0[2] += __shfl_xor(a0[2], off); a0[3] += __shfl_xor(a0[3], off);
            a1[0] += __shfl_xor(a1[0], off); a1[1] += __shfl_xor(a1[1], off);
            a1[2] += __shfl_xor(a1[2], off); a1[3] += __shfl_xor(a1[3], off);
            z0 += __shfl_xor(z0, off);       z1 += __shfl_xor(z1, off);
        }
        if (slot == 0) {
            float zr0 = 1.f / z0, zr1 = 1.f / z1;
            float o0[4] = {a0[0]*zr0, a0[1]*zr0, a0[2]*zr0, a0[3]*zr0};
            float o1[4] = {a1[0]*zr1, a1[1]*zr1, a1[2]*zr1, a1[3]*zr1};
            size_t off0 = ((size_t)(b * SEQ) + q0 + r0) * D_MODEL + h * HD + d16 * 4;
            size_t off1 = ((size_t)(b * SEQ) + q0 + r1) * D_MODEL + h * HD + d16 * 4;
            us4 h0, l0, h1, l1;
#pragma unroll
            for (int e = 0; e < 4; ++e) {
                unsigned short hh0 = f2bf(o0[e]);
                h0[e] = hh0; l0[e] = f2bf(o0[e] - bf2f(hh0));
                unsigned short hh1 = f2bf(o1[e]);
                h1[e] = hh1; l1[e] = f2bf(o1[e] - bf2f(hh1));
            }
            *(us4*)(awsHi + off0) = h0;  *(us4*)(awsLo + off0) = l0;
            *(us4*)(awsHi + off1) = h1;  *(us4*)(awsLo + off1) = l1;
        }
    }
}

// ---------------------------------------------------------------------------
// Workspace map (64 MB), lifetime-aliased:
//  0-32 MB : qhi,qlo,khi,klo (proj->attn); after attn, first 4 MB = WoHi/WoLo
//  32-48   : vws fp32 (proj->attn)
//  48-64   : pre1 W planes (Wq/Wk/Wv hi+lo, 12 MB) during proj;
//            then awsHi(8)+awsLo(8) written by attn, read by oproj.
// ---------------------------------------------------------------------------
extern "C" void kernel_launch(void* const* d_in, const int* in_sizes, int n_in,
                              void* d_out, int out_size, void* d_ws, size_t ws_size,
                              hipStream_t stream)
{
    const float* query = (const float*)d_in[0];
    const float* key   = (const float*)d_in[1];
    const float* value = (const float*)d_in[2];
    const float* Wq    = (const float*)d_in[3];
    const float* bq    = (const float*)d_in[4];
    const float* Wk    = (const float*)d_in[5];
    const float* bk    = (const float*)d_in[6];
    const float* Wv    = (const float*)d_in[7];
    const float* bv    = (const float*)d_in[8];
    const float* Wo    = (const float*)d_in[9];
    const float* bo    = (const float*)d_in[10];
    float* out = (float*)d_out;

    char* wsb = (char*)d_ws;
    const size_t MB = 1024u * 1024u;
    unsigned short* qhi = (unsigned short*)(wsb);
    unsigned short* qlo = (unsigned short*)(wsb + 8 * MB);
    unsigned short* khi = (unsigned short*)(wsb + 16 * MB);
    unsigned short* klo = (unsigned short*)(wsb + 24 * MB);
    float* vws          = (float*)(wsb + 32 * MB);
    // region R (48-64 MB): W planes during proj, aws planes after
    unsigned short* wqh = (unsigned short*)(wsb + 48 * MB);
    unsigned short* wql = (unsigned short*)(wsb + 50 * MB);
    unsigned short* wkh = (unsigned short*)(wsb + 52 * MB);
    unsigned short* wkl = (unsigned short*)(wsb + 54 * MB);
    unsigned short* wvh = (unsigned short*)(wsb + 56 * MB);
    unsigned short* wvl = (unsigned short*)(wsb + 58 * MB);
    unsigned short* awsHi = (unsigned short*)(wsb + 48 * MB);
    unsigned short* awsLo = (unsigned short*)(wsb + 56 * MB);
    // Wo planes: reuse dead qhi region after attn
    unsigned short* woh = (unsigned short*)(wsb);
    unsigned short* wol = (unsigned short*)(wsb + 2 * MB);

    // pre1: Wq/Wk/Wv -> hi/lo planes (1M elems each, 4/thread)
    preconv3_kernel<<<dim3(1024, 3), 256, 0, stream>>>(
        Wq, Wk, Wv, wqh, wql, wkh, wkl, wvh, wvl);

    dim3 g1(D_MODEL / 128, M_TOK / 128, 3);
    proj_qkv_kernel<<<g1, 256, 0, stream>>>(query, key, value,
                                            wqh, wql, wkh, wkl, wvh, wvl,
                                            bq, bk, bv,
                                            qhi, qlo, khi, klo, vws);

    dim3 g2((SEQ / TQ) * BH);
    attn_kernel<<<g2, 512, 0, stream>>>(qhi, qlo, khi, klo, vws, awsHi, awsLo);

    // pre2: Wo -> hi/lo planes (into dead q region)
    preconv1_kernel<<<1024, 256, 0, stream>>>(Wo, woh, wol);

    dim3 g3(D_MODEL / 128, M_TOK / 128);
    oproj_kernel<<<g3, 256, 0, stream>>>(awsHi, awsLo, woh, wol, bo, out);
}

// Round 12
// 667.030 us; speedup vs baseline: 1.0127x; 1.0127x over previous
//
#include <hip/hip_runtime.h>
#include <math.h>

#define D_MODEL 1024
#define SEQ     2048
#define NB      2
#define NH      16
#define HD      64
#define BH      (NB*NH)      // 32
#define M_TOK   (NB*SEQ)     // 4096
#define KSEL    204          // int(2048 * 0.1)
#define TQ      16           // query rows per attention block
#define LCAP    256          // kept-list cap (204 + bin tail headroom)
#define CCAP    96           // candidate-pool cap per row
#define KPW     256          // keys per wave

typedef __attribute__((ext_vector_type(8))) short bf16x8;   // 8 bf16 (4 VGPRs)
typedef __attribute__((ext_vector_type(4))) float f32x4;    // 4 fp32 acc
typedef __attribute__((ext_vector_type(4))) unsigned short us4;
typedef __attribute__((ext_vector_type(8))) unsigned short us8;

__device__ __forceinline__ unsigned short f2bf(float x) {   // RNE fp32->bf16
    unsigned u = __float_as_uint(x);
    return (unsigned short)((u + 0x7FFFu + ((u >> 16) & 1u)) >> 16);
}
__device__ __forceinline__ float bf2f(unsigned short h) {
    return __uint_as_float(((unsigned)h) << 16);
}

// Integer bin map on the 24-bit fixed-point score e (= rint(d * 2^18)):
// bin = clamp((e + 2^22) >> 15, 0, 255). Pure int ALU, identical in passes
// A and B -> bitwise self-consistent selection. NOTE: explicit rint encode
// kept (NOT the magic-number trick): |d| reaches ~20 > 16, outside the
// magic constant's exact range; 24-bit covers |d| < 32.
__device__ __forceinline__ int binOfE(int e) {
    int b = (e + 4194304) >> 15;
    return b < 0 ? 0 : (b > 255 ? 255 : b);
}

// 16B async global->LDS copy. LDS dest is wave-uniform base + lane*16.
__device__ __forceinline__ void gload_lds16(const unsigned short* g,
                                            unsigned short* l) {
    __builtin_amdgcn_global_load_lds(
        (const __attribute__((address_space(1))) unsigned int*)g,
        (__attribute__((address_space(3))) unsigned int*)l, 16, 0, 0);
}

// ---------------------------------------------------------------------------
// Preconvert: fp32 -> (hi, lo) bf16 planes.
// ---------------------------------------------------------------------------
__global__ __launch_bounds__(256) void preconv3_kernel(
    const float* __restrict__ s0, const float* __restrict__ s1,
    const float* __restrict__ s2,
    unsigned short* __restrict__ h0, unsigned short* __restrict__ l0,
    unsigned short* __restrict__ h1, unsigned short* __restrict__ l1,
    unsigned short* __restrict__ h2, unsigned short* __restrict__ l2)
{
    const float* src; unsigned short* hi; unsigned short* lo;
    if (blockIdx.y == 0)      { src = s0; hi = h0; lo = l0; }
    else if (blockIdx.y == 1) { src = s1; hi = h1; lo = l1; }
    else                      { src = s2; hi = h2; lo = l2; }
    int i = (blockIdx.x * 256 + threadIdx.x) * 4;
    float4 v = *(const float4*)(src + i);
    float e[4] = {v.x, v.y, v.z, v.w};
    us4 h, l;
#pragma unroll
    for (int k = 0; k < 4; ++k) {
        unsigned short hh = f2bf(e[k]);
        h[k] = hh; l[k] = f2bf(e[k] - bf2f(hh));
    }
    *(us4*)(hi + i) = h;
    *(us4*)(lo + i) = l;
}

__global__ __launch_bounds__(256) void preconv1_kernel(
    const float* __restrict__ src,
    unsigned short* __restrict__ hi, unsigned short* __restrict__ lo)
{
    int i = (blockIdx.x * 256 + threadIdx.x) * 4;
    float4 v = *(const float4*)(src + i);
    float e[4] = {v.x, v.y, v.z, v.w};
    us4 h, l;
#pragma unroll
    for (int k = 0; k < 4; ++k) {
        unsigned short hh = f2bf(e[k]);
        h[k] = hh; l[k] = f2bf(e[k] - bf2f(hh));
    }
    *(us4*)(hi + i) = h;
    *(us4*)(lo + i) = l;
}

// ---------------------------------------------------------------------------
// Split-bf16 MFMA NT-GEMM, double-buffered LDS 2-phase pipeline (R9 form).
// TERMS=4 restored for q/k (R11 showed proj is staging-bound: the 4->3 cut
// changed time by 0.5 us while costing absmax margin 2.693->2.808e-3).
// ---------------------------------------------------------------------------
template<int MODE, int TERMS, int AF32>
__device__ __forceinline__ void mfma_gemm_body(
    const float* __restrict__ Xf,
    const unsigned short* __restrict__ XH, const unsigned short* __restrict__ XL,
    const unsigned short* __restrict__ WH, const unsigned short* __restrict__ WL,
    const float* __restrict__ bias,
    float* __restrict__ Cf, unsigned short* __restrict__ Chi,
    unsigned short* __restrict__ Clo, unsigned short* lds)
{
    const int tid  = threadIdx.x;
    const int lane = tid & 63;
    const int w    = tid >> 6;
    const int mq   = w & 1;
    const int nq   = w >> 1;
    const int m0   = blockIdx.y * 128;
    const int n0   = blockIdx.x * 128;

    auto stageB = [&](int buf, int k0) {
#pragma unroll
        for (int r2 = 0; r2 < 2; ++r2) {
            int m = tid + 256 * r2;
            int fi = (m & 0x1C0) | ((m & 15) << 2) | ((m >> 4) & 3);
            int row = fi >> 2, k8 = fi & 3;
            size_t g = (size_t)(n0 + row) * D_MODEL + k0 + k8 * 8;
            int ldsb = (r2 * 256 + (tid & ~63)) * 8;   // wave-uniform (shorts)
            gload_lds16(WH + g, lds + buf * 16384 + 8192 + ldsb);
            gload_lds16(WL + g, lds + buf * 16384 + 12288 + ldsb);
        }
    };
    auto stageAcopy = [&](int buf, int k0) {
#pragma unroll
        for (int r2 = 0; r2 < 2; ++r2) {
            int m = tid + 256 * r2;
            int fi = (m & 0x1C0) | ((m & 15) << 2) | ((m >> 4) & 3);
            int row = fi >> 2, k8 = fi & 3;
            size_t g = (size_t)(m0 + row) * D_MODEL + k0 + k8 * 8;
            int ldsb = (r2 * 256 + (tid & ~63)) * 8;
            gload_lds16(XH + g, lds + buf * 16384 + ldsb);
            gload_lds16(XL + g, lds + buf * 16384 + 4096 + ldsb);
        }
    };
    auto loadA = [&](int k0, float4* xa) {
#pragma unroll
        for (int r = 0; r < 4; ++r) {
            int f = tid + 256 * r;
            int row = f >> 3, q4 = f & 7;
            xa[r] = *(const float4*)(Xf + (size_t)(m0 + row) * D_MODEL + k0 + q4 * 4);
        }
    };
    auto writeA = [&](int buf, const float4* xa) {
        unsigned short* Ah = lds + buf * 16384;
        unsigned short* Al = Ah + 4096;
#pragma unroll
        for (int r = 0; r < 4; ++r) {
            int f = tid + 256 * r;
            int row = f >> 3, q4 = f & 7;
            int off = (row >> 4) * 512 + ((row & 15) + (q4 >> 1) * 16) * 8 + (q4 & 1) * 4;
            float ax[4] = {xa[r].x, xa[r].y, xa[r].z, xa[r].w};
            us4 ahv, alv;
#pragma unroll
            for (int e = 0; e < 4; ++e) {
                unsigned short h1 = f2bf(ax[e]);
                ahv[e] = h1; alv[e] = f2bf(ax[e] - bf2f(h1));
            }
            *(us4*)(Ah + off) = ahv;  *(us4*)(Al + off) = alv;
        }
    };

    f32x4 acc[4][4];
#pragma unroll
    for (int i = 0; i < 4; ++i)
#pragma unroll
        for (int j = 0; j < 4; ++j) acc[i][j] = (f32x4){0.f, 0.f, 0.f, 0.f};

    // prologue: stage k0=0 into buffer 0
    float4 xa[4];
    if (AF32) loadA(0, xa);
    stageB(0, 0);
    if (!AF32) stageAcopy(0, 0);
    if (AF32) writeA(0, xa);
    __syncthreads();                          // drains vmcnt + lgkm

    int cur = 0;
    for (int k0 = 0; k0 < D_MODEL; k0 += 32) {
        const bool hasNext = (k0 + 32) < D_MODEL;
        if (hasNext) {
            if (AF32) loadA(k0 + 32, xa);     // issue early (reg-private)
            stageB(cur ^ 1, k0 + 32);         // async into other buffer
            if (!AF32) stageAcopy(cur ^ 1, k0 + 32);
        }

        unsigned short* Ah = lds + cur * 16384;
        unsigned short* Al = Ah + 4096;
        unsigned short* Bh = Ah + 8192;
        unsigned short* Bl = Ah + 12288;
        bf16x8 fah[4], fal[4], fbh[4], fbl[4];
#pragma unroll
        for (int i = 0; i < 4; ++i) {
            fah[i] = *(const bf16x8*)(Ah + (mq * 4 + i) * 512 + lane * 8);
            fal[i] = *(const bf16x8*)(Al + (mq * 4 + i) * 512 + lane * 8);
            fbh[i] = *(const bf16x8*)(Bh + (nq * 4 + i) * 512 + lane * 8);
            fbl[i] = *(const bf16x8*)(Bl + (nq * 4 + i) * 512 + lane * 8);
        }
#pragma unroll
        for (int i = 0; i < 4; ++i)
#pragma unroll
            for (int j = 0; j < 4; ++j) {
                acc[i][j] = __builtin_amdgcn_mfma_f32_16x16x32_bf16(fah[i], fbh[j], acc[i][j], 0, 0, 0);
                acc[i][j] = __builtin_amdgcn_mfma_f32_16x16x32_bf16(fah[i], fbl[j], acc[i][j], 0, 0, 0);
                acc[i][j] = __builtin_amdgcn_mfma_f32_16x16x32_bf16(fal[i], fbh[j], acc[i][j], 0, 0, 0);
                if (TERMS == 4)
                    acc[i][j] = __builtin_amdgcn_mfma_f32_16x16x32_bf16(fal[i], fbl[j], acc[i][j], 0, 0, 0);
            }

        if (hasNext && AF32) writeA(cur ^ 1, xa);   // loads have landed
        __syncthreads();                      // next buffer ready; cur free
        cur ^= 1;
    }

    const int quad = lane >> 4;
    const int rl   = lane & 15;
#pragma unroll
    for (int jt = 0; jt < 4; ++jt) {
        int n = n0 + nq * 64 + jt * 16 + rl;
        float bn = bias[n];
        int h = n >> 6, dd = n & 63;
#pragma unroll
        for (int it = 0; it < 4; ++it) {
#pragma unroll
            for (int r = 0; r < 4; ++r) {
                int m = m0 + mq * 64 + it * 16 + quad * 4 + r;
                float v = acc[it][jt][r] + bn;
                if (MODE == 0) {
                    Cf[(size_t)m * D_MODEL + n] = v;
                } else {
                    int b = m >> 11, s = m & 2047;
                    size_t o = (size_t)(((b << 4) + h) * SEQ + s) * HD + dd;
                    if (MODE == 1) {
                        Cf[o] = v;
                    } else {
                        unsigned short hi = f2bf(v);
                        Chi[o] = hi;
                        Clo[o] = f2bf(v - bf2f(hi));
                    }
                }
            }
        }
    }
}

__global__ __launch_bounds__(256) void proj_qkv_kernel(
    const float* __restrict__ qin, const float* __restrict__ kin, const float* __restrict__ vin,
    const unsigned short* __restrict__ wqh, const unsigned short* __restrict__ wql,
    const unsigned short* __restrict__ wkh, const unsigned short* __restrict__ wkl,
    const unsigned short* __restrict__ wvh, const unsigned short* __restrict__ wvl,
    const float* __restrict__ bq, const float* __restrict__ bk, const float* __restrict__ bv,
    unsigned short* qhi, unsigned short* qlo,
    unsigned short* khi, unsigned short* klo,
    float* vws)
{
    __shared__ unsigned short lds[32768];     // 2 x 32 KB buffers
    if (blockIdx.z == 0)
        mfma_gemm_body<2, 4, 1>(qin, nullptr, nullptr, wqh, wql, bq,
                                nullptr, qhi, qlo, lds);
    else if (blockIdx.z == 1)
        mfma_gemm_body<2, 4, 1>(kin, nullptr, nullptr, wkh, wkl, bk,
                                nullptr, khi, klo, lds);
    else
        mfma_gemm_body<1, 3, 1>(vin, nullptr, nullptr, wvh, wvl, bv,
                                vws, nullptr, nullptr, lds);
}

__global__ __launch_bounds__(256) void oproj_kernel(
    const unsigned short* __restrict__ AH, const unsigned short* __restrict__ AL,
    const unsigned short* __restrict__ woh, const unsigned short* __restrict__ wol,
    const float* __restrict__ bo, float* __restrict__ out)
{
    __shared__ unsigned short lds[32768];
    mfma_gemm_body<0, 3, 0>(nullptr, AH, AL, woh, wol, bo,
                            out, nullptr, nullptr, lds);
}

// ---------------------------------------------------------------------------
// Attention (round 23 = R10 restored + PV fma fold):
//  - single histogram restored (R11's split was +3 us, conflicts unchanged
//    -> Pass-A atomics scattered, never serialized);
//  - register thresholds + PV 16-wide kept (R10: 437 us);
//  - PV weight arg: fma(s, c, -t*c) with wave-uniform -t*c hoisted
//    (v_fmamk_f32: 1 VALU vs sub+mul 2; ulp-level output change only).
// Ledger: occupancy-insensitive (R3/R4), VALU cuts convert ~30% (R5),
// cross-iter pipelining compiler-defeated (R6), 128-reg cliff bounds the
// selection structure (R7), within-iter MLP harvested (R10), atomics
// exonerated (R11). Issue-bound local optimum for this structure.
// ---------------------------------------------------------------------------
__global__ __launch_bounds__(512, 4) void attn_kernel(
    const unsigned short* __restrict__ qhi, const unsigned short* __restrict__ qlo,
    const unsigned short* __restrict__ khi, const unsigned short* __restrict__ klo,
    const float* __restrict__ vws,
    unsigned short* __restrict__ awsHi, unsigned short* __restrict__ awsLo)
{
    __shared__ union __align__(16) UU {
        int hist[TQ][260];                          // 16640 B (pass A + scan)
        struct {
            int2  L[TQ][LCAP];                      // 32768 B {key, d_bits}
            float cand[TQ][CCAP];                   // 6144 B
        } p;                                        // 38912 B
    } u;
    __shared__ int   kneedS[TQ];
    __shared__ int   sbinS[TQ];
    __shared__ int   candCnt[TQ];
    __shared__ int   cnt[TQ];

    const int tid  = threadIdx.x;
    const int lane = tid & 63;
    const int w    = tid >> 6;                      // wave 0..7
    const int quad = lane >> 4;                     // 0..3
    const int rl   = lane & 15;                     // this lane's q row
    const int flat = blockIdx.x;
    const int bh   = (flat & 7) * 4 + ((flat >> 3) & 3);   // XCD swizzle
    const int q0   = (flat >> 5) * TQ;
    const size_t hb = (size_t)bh * SEQ * HD;

    {   // clear histogram + per-row state
        int* hp = &u.hist[0][0];
        for (int i = tid; i < TQ * 260; i += 512) hp[i] = 0;
        if (tid < TQ) { candCnt[tid] = 0; cnt[tid] = 0; }
    }

    // q fragments (B operand; col = q row = rl)
    const size_t qoff = hb + (size_t)(q0 + rl) * HD + quad * 8;
    bf16x8 bqh0 = *(const bf16x8*)(qhi + qoff);
    bf16x8 bql0 = *(const bf16x8*)(qlo + qoff);
    bf16x8 bqh1 = *(const bf16x8*)(qhi + qoff + 32);
    bf16x8 bql1 = *(const bf16x8*)(qlo + qoff + 32);

    const int kbase = w * KPW;
    __syncthreads();                                // clear visible

    // ---- Pass A: unscaled scores -> 24-bit register cache + histogram ----
    unsigned scp[48];
#pragma unroll
    for (int t = 0; t < 16; ++t) {
        const size_t koff = hb + (size_t)(kbase + t * 16 + rl) * HD + quad * 8;
        bf16x8 ah0 = *(const bf16x8*)(khi + koff);
        bf16x8 al0 = *(const bf16x8*)(klo + koff);
        bf16x8 ah1 = *(const bf16x8*)(khi + koff + 32);
        bf16x8 al1 = *(const bf16x8*)(klo + koff + 32);
        f32x4 d0 = {0.f, 0.f, 0.f, 0.f};
        f32x4 d1 = {0.f, 0.f, 0.f, 0.f};
        d0 = __builtin_amdgcn_mfma_f32_16x16x32_bf16(ah0, bqh0, d0, 0, 0, 0);
        d1 = __builtin_amdgcn_mfma_f32_16x16x32_bf16(ah1, bqh1, d1, 0, 0, 0);
        d0 = __builtin_amdgcn_mfma_f32_16x16x32_bf16(ah0, bql0, d0, 0, 0, 0);
        d1 = __builtin_amdgcn_mfma_f32_16x16x32_bf16(ah1, bql1, d1, 0, 0, 0);
        d0 = __builtin_amdgcn_mfma_f32_16x16x32_bf16(al0, bqh0, d0, 0, 0, 0);
        d1 = __builtin_amdgcn_mfma_f32_16x16x32_bf16(al1, bqh1, d1, 0, 0, 0);
        f32x4 d = d0 + d1;
        int e[4];
#pragma unroll
        for (int r = 0; r < 4; ++r) {
            e[r] = (int)__builtin_rintf(d[r] * 262144.f);   // 2^18 encode, RNE
            atomicAdd(&u.hist[rl][binOfE(e[r])], 1);
        }
        // pack 4 x 24-bit -> 3 dwords (little-endian byte stream)
        scp[3*t+0] = ((unsigned)e[0] & 0xFFFFFFu) | ((unsigned)e[1] << 24);
        scp[3*t+1] = (((unsigned)e[1] >> 8) & 0xFFFFu) | ((unsigned)e[2] << 16);
        scp[3*t+2] = (((unsigned)e[2] >> 16) & 0xFFu) | ((unsigned)e[3] << 8);
    }
    __syncthreads();

    // ---- Scan: wave w handles rows w, w+8; suffix-sum over 256 bins ----
#pragma unroll
    for (int half = 0; half < 2; ++half) {
        int r = w + half * 8;
        int4 hv = *(const int4*)&u.hist[r][4 * lane];
        int h0 = hv.x, h1 = hv.y, h2 = hv.z, h3 = hv.w;
        int s3 = h3, s2 = h2 + s3, s1 = h1 + s2, s0 = h0 + s1;
        int acc = s0;
#pragma unroll
        for (int off = 1; off < 64; off <<= 1) {
            int v = __shfl_down(acc, off);
            acc += (lane + off < 64) ? v : 0;
        }
        int ehi = acc - s0;
        int suf0 = ehi + s0, suf1 = ehi + s1, suf2 = ehi + s2, suf3 = ehi + s3;
        int selbin = -1, newkn = 0;
        if      (suf3 >= KSEL) { selbin = 4*lane + 3; newkn = KSEL - (suf3 - h3); }
        else if (suf2 >= KSEL) { selbin = 4*lane + 2; newkn = KSEL - (suf2 - h2); }
        else if (suf1 >= KSEL) { selbin = 4*lane + 1; newkn = KSEL - (suf1 - h1); }
        else if (suf0 >= KSEL) { selbin = 4*lane + 0; newkn = KSEL - (suf0 - h0); }
        int pack = ((selbin + 1) << 16) | (newkn & 0xFFFF);
#pragma unroll
        for (int off = 32; off; off >>= 1) {
            int o = __shfl_xor(pack, off);
            pack = pack > o ? pack : o;
        }
        if (lane == 0) {
            sbinS[r]  = (pack >> 16) - 1;
            kneedS[r] = pack & 0xFFFF;
        }
    }
    __syncthreads();                                // hist reads done

    // ---- Pass B (register replay): push {key, d} where bin >= sbin ----
    {
        const int sb = sbinS[rl];
#pragma unroll
        for (int t = 0; t < 16; ++t) {
            unsigned p0 = scp[3*t+0], p1 = scp[3*t+1], p2 = scp[3*t+2];
            int e[4];
            e[0] = ((int)(p0 << 8)) >> 8;
            e[1] = ((int)(((p1 << 8) | (p0 >> 24)) << 8)) >> 8;
            e[2] = ((int)(((p2 << 16) | (p1 >> 16)) << 8)) >> 8;
            e[3] = ((int)p2) >> 8;
#pragma unroll
            for (int r = 0; r < 4; ++r) {
                int b = binOfE(e[r]);
                if (b >= sb) {
                    float dv = (float)e[r] * (1.f / 262144.f);
                    int key = kbase + t * 16 + quad * 4 + r;
                    int pos = atomicAdd(&cnt[rl], 1);
                    if (pos < LCAP)
                        u.p.L[rl][pos] = make_int2(key, __float_as_int(dv));
                    if (b == sb) {
                        int cp = atomicAdd(&candCnt[rl], 1);
                        if (cp < CCAP) u.p.cand[rl][cp] = dv;
                    }
                }
            }
        }
    }
    __syncthreads();

    // ---- Exact k-th largest among candidates: rows w, w+8 (in-register) ----
    float bestA = -1e30f, bestB = -1e30f;
#pragma unroll
    for (int half = 0; half < 2; ++half) {
        int r = w + half * 8;
        int n = candCnt[r]; if (n > CCAP) n = CCAP;
        int kn = kneedS[r];
        bool  a0 = lane < n, a1 = lane + 64 < n;
        float x0 = a0 ? u.p.cand[r][lane]      : 0.f;
        float x1 = a1 ? u.p.cand[r][lane + 64] : 0.f;
        int g0 = 0, e0 = 0, g1 = 0, e1 = 0;
        for (int j = 0; j < n; ++j) {
            float c = u.p.cand[r][j];
            g0 += (c > x0);  e0 += (c == x0);
            g1 += (c > x1);  e1 += (c == x1);
        }
        float best = -1e30f;
        if (a0 && g0 < kn && g0 + e0 >= kn) best = x0;
        if (a1 && g1 < kn && g1 + e1 >= kn) best = best > x1 ? best : x1;
#pragma unroll
        for (int off = 32; off; off >>= 1) {
            float o = __shfl_xor(best, off);
            best = best > o ? best : o;
        }
        if (half == 0) bestA = best; else bestB = best;
    }
    // No barrier: PV reads only this wave's registers + L (stable since the
    // post-Pass-B barrier); PV writes no LDS.

    // ---- Phase 4: PV gather, 16 keys/iter, 8 independent V-load chains ----
    {
        const int b = bh >> 4, h = bh & 15;
        const int slot = lane >> 4;                 // 0..3: key sub-slot
        const int d16  = lane & 15;                 // dim quarter (float4)
        const float* Vp = vws + hb + d16 * 4;

        const int r0 = w, r1 = w + 8;
        int n0 = cnt[r0]; if (n0 > LCAP) n0 = LCAP;
        int n1 = cnt[r1]; if (n1 > LCAP) n1 = LCAP;
        const float t0 = bestA, t1 = bestB;
        const float C2 = 0.1803368801f;             // 1/(8*ln2) * ... (exp2 scale)
        const float ntc0 = -t0 * C2, ntc1 = -t1 * C2;   // wave-uniform
        const int nmax = n0 > n1 ? n0 : n1;
        f32x4 a0 = {0.f,0.f,0.f,0.f}, a1 = {0.f,0.f,0.f,0.f};
        float z0 = 0.f, z1 = 0.f;

        for (int j = 0; j < nmax; j += 16) {
            int ia = j + slot, ib = j + 4 + slot;
            int ic = j + 8 + slot, id = j + 12 + slot;
            int2 p0a = u.p.L[r0][ia < n0 ? ia : 0];
            int2 p0b = u.p.L[r0][ib < n0 ? ib : 0];
            int2 p0c = u.p.L[r0][ic < n0 ? ic : 0];
            int2 p0d = u.p.L[r0][id < n0 ? id : 0];
            int2 p1a = u.p.L[r1][ia < n1 ? ia : 0];
            int2 p1b = u.p.L[r1][ib < n1 ? ib : 0];
            int2 p1c = u.p.L[r1][ic < n1 ? ic : 0];
            int2 p1d = u.p.L[r1][id < n1 ? id : 0];
            float s0a = __int_as_float(p0a.y), s0b = __int_as_float(p0b.y);
            float s0c = __int_as_float(p0c.y), s0d = __int_as_float(p0d.y);
            float s1a = __int_as_float(p1a.y), s1b = __int_as_float(p1b.y);
            float s1c = __int_as_float(p1c.y), s1d = __int_as_float(p1d.y);
            float w0a = ((ia < n0) && (s0a >= t0))
                        ? __builtin_amdgcn_exp2f(__builtin_fmaf(s0a, C2, ntc0)) : 0.f;
            float w0b = ((ib < n0) && (s0b >= t0))
                        ? __builtin_amdgcn_exp2f(__builtin_fmaf(s0b, C2, ntc0)) : 0.f;
            float w0c = ((ic < n0) && (s0c >= t0))
                        ? __builtin_amdgcn_exp2f(__builtin_fmaf(s0c, C2, ntc0)) : 0.f;
            float w0d = ((id < n0) && (s0d >= t0))
                        ? __builtin_amdgcn_exp2f(__builtin_fmaf(s0d, C2, ntc0)) : 0.f;
            float w1a = ((ia < n1) && (s1a >= t1))
                        ? __builtin_amdgcn_exp2f(__builtin_fmaf(s1a, C2, ntc1)) : 0.f;
            float w1b = ((ib < n1) && (s1b >= t1))
                        ? __builtin_amdgcn_exp2f(__builtin_fmaf(s1b, C2, ntc1)) : 0.f;
            float w1c = ((ic < n1) && (s1c >= t1))
                        ? __builtin_amdgcn_exp2f(__builtin_fmaf(s1c, C2, ntc1)) : 0.f;
            float w1d = ((id < n1) && (s1d >= t1))
                        ? __builtin_amdgcn_exp2f(__builtin_fmaf(s1d, C2, ntc1)) : 0.f;
            float4 v0a = *(const float4*)(Vp + (size_t)p0a.x * HD);
            float4 v0b = *(const float4*)(Vp + (size_t)p0b.x * HD);
            float4 v0c = *(const float4*)(Vp + (size_t)p0c.x * HD);
            float4 v0d = *(const float4*)(Vp + (size_t)p0d.x * HD);
            float4 v1a = *(const float4*)(Vp + (size_t)p1a.x * HD);
            float4 v1b = *(const float4*)(Vp + (size_t)p1b.x * HD);
            float4 v1c = *(const float4*)(Vp + (size_t)p1c.x * HD);
            float4 v1d = *(const float4*)(Vp + (size_t)p1d.x * HD);
            a0[0] += (w0a * v0a.x + w0b * v0b.x) + (w0c * v0c.x + w0d * v0d.x);
            a0[1] += (w0a * v0a.y + w0b * v0b.y) + (w0c * v0c.y + w0d * v0d.y);
            a0[2] += (w0a * v0a.z + w0b * v0b.z) + (w0c * v0c.z + w0d * v0d.z);
            a0[3] += (w0a * v0a.w + w0b * v0b.w) + (w0c * v0c.w + w0d * v0d.w);
            a1[0] += (w1a * v1a.x + w1b * v1b.x) + (w1c * v1c.x + w1d * v1d.x);
            a1[1] += (w1a * v1a.y + w1b * v1b.y) + (w1c * v1c.y + w1d * v1d.y);
            a1[2] += (w1a * v1a.z + w1b * v1b.z) + (w1c * v1c.z + w1d * v1d.z);
            a1[3] += (w1a * v1a.w + w1b * v1b.w) + (w1c * v1c.w + w1d * v1d.w);
            z0 += (w0a + w0b) + (w0c + w0d);
            z1 += (w1a + w1b) + (w1c + w1d);
        }
#pragma unroll
        for (int off = 16; off < 64; off <<= 1) {
            a0[0] += __shfl_xor(a0[0], off); a0[1] += __shfl_xor(a0[1], off);
            a0[2] += __shfl_xor(a0[2], off); a0[3] += __shfl_xor(a0[3], off);
            a1[0] += __shfl_xor(a1[0], off); a1[1] += __shfl_xor(a1[1], off);
            a1[2] += __shfl_xor(a1[2], off); a1[3] += __shfl_xor(a1[3], off);
            z0 += __shfl_xor(z0, off);       z1 += __shfl_xor(z1, off);
        }
        if (slot == 0) {
            float zr0 = 1.f / z0, zr1 = 1.f / z1;
            float o0[4] = {a0[0]*zr0, a0[1]*zr0, a0[2]*zr0, a0[3]*zr0};
            float o1[4] = {a1[0]*zr1, a1[1]*zr1, a1[2]*zr1, a1[3]*zr1};
            size_t off0 = ((size_t)(b * SEQ) + q0 + r0) * D_MODEL + h * HD + d16 * 4;
            size_t off1 = ((size_t)(b * SEQ) + q0 + r1) * D_MODEL + h * HD + d16 * 4;
            us4 h0, l0, h1, l1;
#pragma unroll
            for (int e = 0; e < 4; ++e) {
                unsigned short hh0 = f2bf(o0[e]);
                h0[e] = hh0; l0[e] = f2bf(o0[e] - bf2f(hh0));
                unsigned short hh1 = f2bf(o1[e]);
                h1[e] = hh1; l1[e] = f2bf(o1[e] - bf2f(hh1));
            }
            *(us4*)(awsHi + off0) = h0;  *(us4*)(awsLo + off0) = l0;
            *(us4*)(awsHi + off1) = h1;  *(us4*)(awsLo + off1) = l1;
        }
    }
}

// ---------------------------------------------------------------------------
// Workspace map (64 MB), lifetime-aliased:
//  0-32 MB : qhi,qlo,khi,klo (proj->attn); after attn, first 4 MB = WoHi/WoLo
//  32-48   : vws fp32 (proj->attn)
//  48-64   : pre1 W planes (Wq/Wk/Wv hi+lo, 12 MB) during proj;
//            then awsHi(8)+awsLo(8) written by attn, read by oproj.
// ---------------------------------------------------------------------------
extern "C" void kernel_launch(void* const* d_in, const int* in_sizes, int n_in,
                              void* d_out, int out_size, void* d_ws, size_t ws_size,
                              hipStream_t stream)
{
    const float* query = (const float*)d_in[0];
    const float* key   = (const float*)d_in[1];
    const float* value = (const float*)d_in[2];
    const float* Wq    = (const float*)d_in[3];
    const float* bq    = (const float*)d_in[4];
    const float* Wk    = (const float*)d_in[5];
    const float* bk    = (const float*)d_in[6];
    const float* Wv    = (const float*)d_in[7];
    const float* bv    = (const float*)d_in[8];
    const float* Wo    = (const float*)d_in[9];
    const float* bo    = (const float*)d_in[10];
    float* out = (float*)d_out;

    char* wsb = (char*)d_ws;
    const size_t MB = 1024u * 1024u;
    unsigned short* qhi = (unsigned short*)(wsb);
    unsigned short* qlo = (unsigned short*)(wsb + 8 * MB);
    unsigned short* khi = (unsigned short*)(wsb + 16 * MB);
    unsigned short* klo = (unsigned short*)(wsb + 24 * MB);
    float* vws          = (float*)(wsb + 32 * MB);
    // region R (48-64 MB): W planes during proj, aws planes after
    unsigned short* wqh = (unsigned short*)(wsb + 48 * MB);
    unsigned short* wql = (unsigned short*)(wsb + 50 * MB);
    unsigned short* wkh = (unsigned short*)(wsb + 52 * MB);
    unsigned short* wkl = (unsigned short*)(wsb + 54 * MB);
    unsigned short* wvh = (unsigned short*)(wsb + 56 * MB);
    unsigned short* wvl = (unsigned short*)(wsb + 58 * MB);
    unsigned short* awsHi = (unsigned short*)(wsb + 48 * MB);
    unsigned short* awsLo = (unsigned short*)(wsb + 56 * MB);
    // Wo planes: reuse dead qhi region after attn
    unsigned short* woh = (unsigned short*)(wsb);
    unsigned short* wol = (unsigned short*)(wsb + 2 * MB);

    // pre1: Wq/Wk/Wv -> hi/lo planes (1M elems each, 4/thread)
    preconv3_kernel<<<dim3(1024, 3), 256, 0, stream>>>(
        Wq, Wk, Wv, wqh, wql, wkh, wkl, wvh, wvl);

    dim3 g1(D_MODEL / 128, M_TOK / 128, 3);
    proj_qkv_kernel<<<g1, 256, 0, stream>>>(query, key, value,
                                            wqh, wql, wkh, wkl, wvh, wvl,
                                            bq, bk, bv,
                                            qhi, qlo, khi, klo, vws);

    dim3 g2((SEQ / TQ) * BH);
    attn_kernel<<<g2, 512, 0, stream>>>(qhi, qlo, khi, klo, vws, awsHi, awsLo);

    // pre2: Wo -> hi/lo planes (into dead q region)
    preconv1_kernel<<<1024, 256, 0, stream>>>(Wo, woh, wol);

    dim3 g3(D_MODEL / 128, M_TOK / 128);
    oproj_kernel<<<g3, 256, 0, stream>>>(awsHi, awsLo, woh, wol, bo, out);
}